// Round 11
// baseline (477.692 us; speedup 1.0000x reference)
//
#include <hip/hip_runtime.h>
#include <hip/hip_bf16.h>

#define BN_EPS 1e-5f

typedef short bf16x8 __attribute__((ext_vector_type(8)));
typedef float f32x4 __attribute__((ext_vector_type(4)));

static __device__ __forceinline__ unsigned short f2bf(float f) {
    unsigned u = __float_as_uint(f);
    unsigned r = (u + 0x7FFF + ((u >> 16) & 1)) >> 16;
    return (unsigned short)r;
}
static __device__ __forceinline__ float bf2f(unsigned short s) {
    return __uint_as_float((unsigned)s << 16);
}
__device__ __forceinline__ int pad8i(int c) { return (c + 7) & ~7; }

#define BIN_SHIFT 9
#define BIN_NODES 512
#define P1_CHUNK 8192
#define IMG_CAP 12288

// ---------------- exclusive scan over PADDED counts (3-pass, chunk = 1024) ----
#define SCAN_CHUNK 1024

__global__ void scan_block_sums(const int* __restrict__ cnt, int* __restrict__ bsums, int n) {
    __shared__ int sdata[256];
    int b = blockIdx.x, t = threadIdx.x;
    int base = b * SCAN_CHUNK;
    int s = 0;
    for (int i = t; i < SCAN_CHUNK; i += 256) {
        int idx = base + i;
        if (idx < n) s += pad8i(cnt[idx]);
    }
    sdata[t] = s;
    __syncthreads();
    for (int off = 128; off > 0; off >>= 1) {
        if (t < off) sdata[t] += sdata[t + off];
        __syncthreads();
    }
    if (t == 0) bsums[b] = sdata[0];
}

__global__ void scan_exclusive_bsums(int* __restrict__ bsums, int nb) {
    if (threadIdx.x == 0 && blockIdx.x == 0) {
        int acc = 0;
        for (int i = 0; i < nb; i++) { int v = bsums[i]; bsums[i] = acc; acc += v; }
    }
}

__global__ void scan_write(const int* __restrict__ cnt, const int* __restrict__ bsums,
                           int* __restrict__ row_start, int n) {
    __shared__ int sdata[256];
    int b = blockIdx.x, t = threadIdx.x;
    int base = b * SCAN_CHUNK + t * 4;
    int v0 = 0, v1 = 0, v2 = 0, v3 = 0;
    if (base + 0 < n) v0 = pad8i(cnt[base + 0]);
    if (base + 1 < n) v1 = pad8i(cnt[base + 1]);
    if (base + 2 < n) v2 = pad8i(cnt[base + 2]);
    if (base + 3 < n) v3 = pad8i(cnt[base + 3]);
    int tsum = v0 + v1 + v2 + v3;
    sdata[t] = tsum;
    __syncthreads();
    for (int off = 1; off < 256; off <<= 1) {       // inclusive Hillis-Steele
        int x = (t >= off) ? sdata[t - off] : 0;
        __syncthreads();
        sdata[t] += x;
        __syncthreads();
    }
    int excl = sdata[t] - tsum + bsums[b];
    if (base + 0 < n) row_start[base + 0] = excl;
    if (base + 1 < n) row_start[base + 1] = excl + v0;
    if (base + 2 < n) row_start[base + 2] = excl + v0 + v1;
    if (base + 3 < n) row_start[base + 3] = excl + v0 + v1 + v2;
    if (n - 1 >= base && n - 1 < base + 4)          // finalize total (padded end)
        row_start[n] = excl + v0 + v1 + v2 + v3;
}

// ---------------- bin-level histogram: LDS hist -> few global atomics -------
__global__ __launch_bounds__(256) void binhist_kernel(const int* __restrict__ dst,
                                                      int* __restrict__ bincnt,
                                                      int e, int nbins) {
    __shared__ int hist[256];
    int t = threadIdx.x;
    hist[t] = 0;
    __syncthreads();
    int c0 = blockIdx.x * P1_CHUNK;
    int iend = c0 + P1_CHUNK; if (iend > e) iend = e;
    for (int i = c0 + t; i < iend; i += 256)
        atomicAdd(&hist[dst[i] >> BIN_SHIFT], 1);
    __syncthreads();
    if (t < nbins && hist[t] > 0) atomicAdd(&bincnt[t], hist[t]);
}

__global__ void scan_small(const int* __restrict__ in, int* __restrict__ out, int m) {
    if (threadIdx.x == 0 && blockIdx.x == 0) {
        int a = 0;
        for (int i = 0; i < m; i++) { out[i] = a; a += in[i]; }
        out[m] = a;
    }
}

// ---------------- phase 1: partition edges into 512-node bins --------------
__global__ __launch_bounds__(256) void phase1_kernel(
        const int* __restrict__ src, const int* __restrict__ dst,
        const int* __restrict__ bstart_e, int* __restrict__ bincur,
        int* __restrict__ ebuf, int e, int nbins) {
    __shared__ int hist[256], base[256], cur[256];
    int t = threadIdx.x;
    int c0 = blockIdx.x * P1_CHUNK;
    int iend = c0 + P1_CHUNK; if (iend > e) iend = e;
    hist[t] = 0;
    __syncthreads();
    for (int i = c0 + t; i < iend; i += 256)
        atomicAdd(&hist[dst[i] >> BIN_SHIFT], 1);
    __syncthreads();
    if (t < nbins && hist[t] > 0)
        base[t] = bstart_e[t] + atomicAdd(&bincur[t], hist[t]);
    cur[t] = 0;
    __syncthreads();
    for (int i = c0 + t; i < iend; i += 256) {
        int s = src[i], d = dst[i];
        int b = d >> BIN_SHIFT;
        int r = atomicAdd(&cur[b], 1);
        ebuf[base[b] + r] = s | ((d & (BIN_NODES - 1)) << 17);
    }
}

// ---------------- per-node counts + dinv from binned edges (LDS only) ------
__global__ __launch_bounds__(256) void bincount_kernel(
        const int* __restrict__ ebuf, const int* __restrict__ bstart_e,
        int* __restrict__ cnt, float* __restrict__ dinv, int n) {
    __shared__ int c512[BIN_NODES];
    int b = blockIdx.x, t = threadIdx.x;
    for (int k = t; k < BIN_NODES; k += 256) c512[k] = 0;
    __syncthreads();
    int e0 = bstart_e[b], e1 = bstart_e[b + 1];
    for (int j = e0 + t; j < e1; j += 256)
        atomicAdd(&c512[ebuf[j] >> 17], 1);
    __syncthreads();
    int n0 = b * BIN_NODES;
    for (int k = t; k < BIN_NODES; k += 256) {
        int i = n0 + k;
        if (i < n) {
            int c = c512[k];
            cnt[i] = c;
            dinv[i] = rsqrtf((float)(c + 1));
        }
    }
}

// ---------------- phase 2: per-bin CSR build in LDS, coalesced write-out ----
__global__ __launch_bounds__(256) void phase2_kernel(
        const int* __restrict__ ebuf, const int* __restrict__ bstart_e,
        const int* __restrict__ row_start, int* __restrict__ csr,
        int* __restrict__ gcursor, int n, int sentinel) {
    __shared__ int image[IMG_CAP];
    __shared__ int lcur[BIN_NODES];
    int b = blockIdx.x, t = threadIdx.x;
    int n0 = b * BIN_NODES;
    int n1 = n0 + BIN_NODES; if (n1 > n) n1 = n;
    int rbase = row_start[n0];
    int rspan = row_start[n1] - rbase;
    int e0 = bstart_e[b], e1 = bstart_e[b + 1];
    for (int k = t; k < BIN_NODES; k += 256) lcur[k] = 0;
    if (rspan <= IMG_CAP) {
        for (int k = t; k < rspan; k += 256) image[k] = sentinel;
        __syncthreads();
        for (int j = e0 + t; j < e1; j += 256) {
            int en = ebuf[j];
            int s = en & 0x1FFFF;
            int dl = en >> 17;
            int pos = row_start[n0 + dl] - rbase + atomicAdd(&lcur[dl], 1);
            image[pos] = s;
        }
        __syncthreads();
        for (int k = t; k < rspan; k += 256) csr[rbase + k] = image[k];
    } else {                                        // statistically never
        __syncthreads();
        for (int j = e0 + t; j < e1; j += 256) {
            int en = ebuf[j];
            int s = en & 0x1FFFF;
            int dl = en >> 17;
            int pos = row_start[n0 + dl] + atomicAdd(&gcursor[n0 + dl], 1);
            csr[pos] = s;
        }
        __syncthreads();
        for (int k = t; k < n1 - n0; k += 256) {    // fill pads with sentinel
            int node = n0 + k;
            int c = gcursor[node];
            for (int pos = row_start[node] + c; pos < row_start[node + 1]; pos++)
                csr[pos] = sentinel;
        }
    }
}

// ---------------- MFMA linear: hs[N,64] = dinv[r] * (in[N,K] @ w[K,64]) ----
// block = 256 thr = 4 waves; 64-row tile; xs + wT staged bf16 in LDS.
// Operand order: A = wT rows (m = feature), B = xs rows (n = x-row) so each
// lane owns 4 consecutive FEATURES of one row -> ushort4 stores.
template<int K, bool BF16IN>
__global__ __launch_bounds__(256) void lin_mfma(const void* __restrict__ in_,
                                                const float* __restrict__ w,
                                                const float* __restrict__ dinv,
                                                unsigned short* __restrict__ outbf, int n) {
    constexpr int XS = K + 8;                       // shorts; keeps 16B row alignment
    __shared__ unsigned short xs[64 * XS];
    __shared__ unsigned short wt[64 * XS];          // transposed w: wt[col][k]
    int t = threadIdx.x;
    int row0 = blockIdx.x * 64;
    int nrows = n - row0; if (nrows > 64) nrows = 64;

    {   // stage w transposed (float4 reads; scattered 2B LDS writes - small)
        const float4* w4 = (const float4*)w;
        for (int idx = t; idx < K * 16; idx += 256) {
            int k = idx >> 4, c4 = (idx & 15) * 4;
            float4 v = w4[idx];
            wt[(c4 + 0) * XS + k] = f2bf(v.x);
            wt[(c4 + 1) * XS + k] = f2bf(v.y);
            wt[(c4 + 2) * XS + k] = f2bf(v.z);
            wt[(c4 + 3) * XS + k] = f2bf(v.w);
        }
    }
    if constexpr (BF16IN) {
        const uint4* in4 = (const uint4*)((const unsigned short*)in_ + (size_t)row0 * K);
        int total8 = nrows * (K / 8);
        for (int idx = t; idx < total8; idx += 256) {
            int r = idx / (K / 8), kk = idx - r * (K / 8);
            uint4 v = in4[idx];
            *(uint4*)&xs[r * XS + kk * 8] = v;      // 16B aligned
        }
    } else {
        const float4* in4 = (const float4*)((const float*)in_ + (size_t)row0 * K);
        int total4 = nrows * (K / 4);
        for (int idx = t; idx < total4; idx += 256) {
            int r = idx / (K / 4), kk = idx - r * (K / 4);
            float4 v = in4[idx];
            ushort4 s4;
            s4.x = f2bf(v.x); s4.y = f2bf(v.y); s4.z = f2bf(v.z); s4.w = f2bf(v.w);
            *(ushort4*)&xs[r * XS + kk * 4] = s4;   // 8B aligned
        }
    }
    __syncthreads();

    int lane = t & 63;
    int wid = t >> 6;
    int quad = lane >> 4;
    int l15 = lane & 15;

    f32x4 acc[4];
#pragma unroll
    for (int cg = 0; cg < 4; cg++) acc[cg] = (f32x4){0.f, 0.f, 0.f, 0.f};

    const unsigned short* xrow = &xs[(wid * 16 + l15) * XS + quad * 8];
#pragma unroll
    for (int kc = 0; kc < K / 32; kc++) {
        bf16x8 bfrag = *(const bf16x8*)(xrow + kc * 32);
#pragma unroll
        for (int cg = 0; cg < 4; cg++) {
            bf16x8 afrag = *(const bf16x8*)&wt[(cg * 16 + l15) * XS + kc * 32 + quad * 8];
            acc[cg] = __builtin_amdgcn_mfma_f32_16x16x32_bf16(afrag, bfrag, acc[cg], 0, 0, 0);
        }
    }

    int grow = row0 + wid * 16 + l15;               // lane owns one x-row
    if (grow < n) {
        float dv = dinv[grow];
#pragma unroll
        for (int cg = 0; cg < 4; cg++) {            // features cg*16 + quad*4 .. +3
            ushort4 st;
            st.x = f2bf(acc[cg][0] * dv);
            st.y = f2bf(acc[cg][1] * dv);
            st.z = f2bf(acc[cg][2] * dv);
            st.w = f2bf(acc[cg][3] * dv);
            *(ushort4*)&outbf[(size_t)grow * 64 + cg * 16 + quad * 4] = st;
        }
    }
}

// ---------------- aggregation + bias + BN + ReLU (quad-gather) -------------
// one wave per node; quad q loads row csr[j+q] (8 B/lane = 4 features) ->
// 4 rows per instruction; per-lane 4-feature partials; cross-quad shfl_xor
// reduce; quad 0 stores ushort4.
__global__ __launch_bounds__(256) void agg_kernel(
        const unsigned short* __restrict__ hs, const int* __restrict__ row_start,
        const int* __restrict__ csr, const float* __restrict__ dinv,
        const float* __restrict__ bias, const float* __restrict__ gam,
        const float* __restrict__ bet, const float* __restrict__ mu,
        const float* __restrict__ var,
        unsigned short* __restrict__ out, int n) {
    int i = blockIdx.x * 4 + (threadIdx.x >> 6);
    int lane = threadIdx.x & 63;
    int l15 = lane & 15, quad = lane >> 4;
    if (i >= n) return;
    float a0 = 0.f, a1 = 0.f, a2 = 0.f, a3 = 0.f;
    int rs = row_start[i], re = row_start[i + 1];   // multiples of 8
    for (int j = rs; j < re; j += 8) {
        int s0 = csr[j + quad];                     // 4 distinct rows per wave
        int s1 = csr[j + 4 + quad];
        uint2 g0 = *(const uint2*)&hs[(size_t)s0 * 64 + l15 * 4];
        uint2 g1 = *(const uint2*)&hs[(size_t)s1 * 64 + l15 * 4];
        a0 += __uint_as_float(g0.x << 16) + __uint_as_float(g1.x << 16);
        a1 += __uint_as_float(g0.x & 0xffff0000u) + __uint_as_float(g1.x & 0xffff0000u);
        a2 += __uint_as_float(g0.y << 16) + __uint_as_float(g1.y << 16);
        a3 += __uint_as_float(g0.y & 0xffff0000u) + __uint_as_float(g1.y & 0xffff0000u);
    }
    // reduce across quads (features are per-l15, partial over rows)
    a0 += __shfl_xor(a0, 16, 64); a0 += __shfl_xor(a0, 32, 64);
    a1 += __shfl_xor(a1, 16, 64); a1 += __shfl_xor(a1, 32, 64);
    a2 += __shfl_xor(a2, 16, 64); a2 += __shfl_xor(a2, 32, 64);
    a3 += __shfl_xor(a3, 16, 64); a3 += __shfl_xor(a3, 32, 64);
    // self-loop (pre-scaled row i)
    uint2 sg = *(const uint2*)&hs[(size_t)i * 64 + l15 * 4];
    a0 += __uint_as_float(sg.x << 16);
    a1 += __uint_as_float(sg.x & 0xffff0000u);
    a2 += __uint_as_float(sg.y << 16);
    a3 += __uint_as_float(sg.y & 0xffff0000u);
    if (quad == 0) {
        int f = l15 * 4;
        float di = dinv[i];
        float4 gm = *(const float4*)&gam[f];
        float4 vr = *(const float4*)&var[f];
        float4 bi = *(const float4*)&bias[f];
        float4 m4 = *(const float4*)&mu[f];
        float4 be = *(const float4*)&bet[f];
        float r0 = (a0 * di + bi.x - m4.x) * (gm.x * rsqrtf(vr.x + BN_EPS)) + be.x;
        float r1 = (a1 * di + bi.y - m4.y) * (gm.y * rsqrtf(vr.y + BN_EPS)) + be.y;
        float r2 = (a2 * di + bi.z - m4.z) * (gm.z * rsqrtf(vr.z + BN_EPS)) + be.z;
        float r3 = (a3 * di + bi.w - m4.w) * (gm.w * rsqrtf(vr.w + BN_EPS)) + be.w;
        ushort4 st;
        st.x = f2bf(r0 > 0.f ? r0 : 0.f);
        st.y = f2bf(r1 > 0.f ? r1 : 0.f);
        st.z = f2bf(r2 > 0.f ? r2 : 0.f);
        st.w = f2bf(r3 > 0.f ? r3 : 0.f);
        *(ushort4*)&out[(size_t)i * 64 + f] = st;
    }
}

// ---------------- pool stage 1: node-parallel segmented sum (bf16 in) ------
#define POOL_CHUNK 64
__global__ __launch_bounds__(256) void pool_kernel(const unsigned short* __restrict__ h,
                                                   const int* __restrict__ batch,
                                                   float* __restrict__ pooled, int n) {
    int wid = blockIdx.x * 4 + (threadIdx.x >> 6);
    int lane = threadIdx.x & 63;
    int start = wid * POOL_CHUNK;
    if (start >= n) return;
    int end = start + POOL_CHUNK; if (end > n) end = n;
    int cur = batch[start];
    float acc = 0.f;
    for (int i = start; i < end; i++) {
        int b = batch[i];
        if (b != cur) {
            atomicAdd(&pooled[(size_t)cur * 64 + lane], acc);
            acc = 0.f; cur = b;
        }
        acc += bf2f(h[(size_t)i * 64 + lane]);
    }
    atomicAdd(&pooled[(size_t)cur * 64 + lane], acc);
}

// ---------------- pool stage 2: tiny MLP per graph ----------------
__global__ void mlp_kernel(const float* __restrict__ pooled,
                           const float* __restrict__ l1w, const float* __restrict__ l1b,
                           const float* __restrict__ l2w, const float* __restrict__ l2b,
                           float* __restrict__ out) {
    int g = blockIdx.x;
    int lane = threadIdx.x;
    __shared__ float p[64];
    __shared__ float h1[32];
    p[lane] = pooled[(size_t)g * 64 + lane];
    __syncthreads();
    if (lane < 32) {
        float a = l1b[lane];
#pragma unroll 8
        for (int k = 0; k < 64; k++) a += p[k] * l1w[k * 32 + lane];
        h1[lane] = a > 0.f ? a : 0.f;
    }
    __syncthreads();
    if (lane < 2) {
        float a = l2b[lane];
#pragma unroll 8
        for (int j = 0; j < 32; j++) a += h1[j] * l2w[j * 2 + lane];
        out[g * 2 + lane] = a;
    }
}

extern "C" void kernel_launch(void* const* d_in, const int* in_sizes, int n_in,
                              void* d_out, int out_size, void* d_ws, size_t ws_size,
                              hipStream_t stream) {
    const float* x     = (const float*)d_in[0];
    const int*   ei    = (const int*)d_in[1];
    const int*   batch = (const int*)d_in[2];
    const float* w0 = (const float*)d_in[3];
    const float* b0 = (const float*)d_in[4];
    const float* w1 = (const float*)d_in[5];
    const float* b1 = (const float*)d_in[6];
    const float* w2 = (const float*)d_in[7];
    const float* b2 = (const float*)d_in[8];
    const float* g0 = (const float*)d_in[9];
    const float* be0 = (const float*)d_in[10];
    const float* m0 = (const float*)d_in[11];
    const float* v0 = (const float*)d_in[12];
    const float* g1 = (const float*)d_in[13];
    const float* be1 = (const float*)d_in[14];
    const float* m1 = (const float*)d_in[15];
    const float* v1 = (const float*)d_in[16];
    const float* g2 = (const float*)d_in[17];
    const float* be2 = (const float*)d_in[18];
    const float* m2 = (const float*)d_in[19];
    const float* v2 = (const float*)d_in[20];
    const float* l1w = (const float*)d_in[21];
    const float* l1b = (const float*)d_in[22];
    const float* l2w = (const float*)d_in[23];
    const float* l2b = (const float*)d_in[24];
    float* out = (float*)d_out;

    const int N = in_sizes[2];
    const int E = in_sizes[1] / 2;
    const int G = out_size / 2;
    const int NBINS = (N + BIN_NODES - 1) / BIN_NODES;

    const int* src = ei;
    const int* dst = ei + E;

    // workspace layout
    char* p = (char*)d_ws;
    auto alloc = [&](size_t bytes) -> void* {
        void* r = (void*)p;
        p += (bytes + 255) & ~(size_t)255;
        return r;
    };
    const size_t CSR_CAP = ((size_t)E + 8 * (size_t)N + 3) & ~(size_t)3;
    float* dinvp    = (float*)alloc((size_t)N * 4);
    int*   cnt      = (int*)alloc((size_t)N * 4);
    int*   row_start= (int*)alloc((size_t)(N + 1) * 4);
    int*   cursor   = (int*)alloc((size_t)N * 4);
    int    NB       = (N + SCAN_CHUNK - 1) / SCAN_CHUNK;
    int*   bsums    = (int*)alloc((size_t)NB * 4);
    int*   bincnt   = (int*)alloc((size_t)NBINS * 4);
    int*   bstart_e = (int*)alloc((size_t)(NBINS + 1) * 4);
    int*   bincur   = (int*)alloc((size_t)NBINS * 4);
    int*   ebuf     = (int*)alloc((size_t)E * 4);
    int*   csr      = (int*)alloc(CSR_CAP * 4);
    unsigned short* h_a = (unsigned short*)alloc((size_t)(N + 1) * 64 * 2); // +sentinel row
    unsigned short* h_b = (unsigned short*)alloc((size_t)N * 64 * 2);       // bf16 agg out
    float* pooled   = (float*)alloc((size_t)G * 64 * 4);
    (void)ws_size;

    // ---- graph preprocessing ----
    hipMemsetAsync(cursor, 0, (size_t)N * 4, stream);
    hipMemsetAsync(bincnt, 0, (size_t)NBINS * 4, stream);
    hipMemsetAsync(bincur, 0, (size_t)NBINS * 4, stream);
    hipMemsetAsync(pooled, 0, (size_t)G * 64 * 4, stream);
    hipMemsetAsync(h_a + (size_t)N * 64, 0, 64 * 2, stream);   // zero sentinel row
    const int nchunks = (E + P1_CHUNK - 1) / P1_CHUNK;
    binhist_kernel<<<nchunks, 256, 0, stream>>>(dst, bincnt, E, NBINS);
    scan_small<<<1, 64, 0, stream>>>(bincnt, bstart_e, NBINS);
    phase1_kernel<<<nchunks, 256, 0, stream>>>(src, dst, bstart_e, bincur, ebuf, E, NBINS);
    bincount_kernel<<<NBINS, 256, 0, stream>>>(ebuf, bstart_e, cnt, dinvp, N);
    scan_block_sums<<<NB, 256, 0, stream>>>(cnt, bsums, N);
    scan_exclusive_bsums<<<1, 64, 0, stream>>>(bsums, NB);
    scan_write<<<NB, 256, 0, stream>>>(cnt, bsums, row_start, N);
    phase2_kernel<<<NBINS, 256, 0, stream>>>(ebuf, bstart_e, row_start, csr,
                                             cursor, N, N);

    const int nblk = (N + 3) / 4;
    const int lblk = (N + 63) / 64;
    // ---- layer 0 ----
    lin_mfma<128, false><<<lblk, 256, 0, stream>>>(x, w0, dinvp, h_a, N);
    agg_kernel<<<nblk, 256, 0, stream>>>(h_a, row_start, csr, dinvp,
                                         b0, g0, be0, m0, v0, h_b, N);
    // ---- layer 1 ----
    lin_mfma<64, true><<<lblk, 256, 0, stream>>>(h_b, w1, dinvp, h_a, N);
    agg_kernel<<<nblk, 256, 0, stream>>>(h_a, row_start, csr, dinvp,
                                         b1, g1, be1, m1, v1, h_b, N);
    // ---- layer 2 ----
    lin_mfma<64, true><<<lblk, 256, 0, stream>>>(h_b, w2, dinvp, h_a, N);
    agg_kernel<<<nblk, 256, 0, stream>>>(h_a, row_start, csr, dinvp,
                                         b2, g2, be2, m2, v2, h_b, N);
    // ---- pool + MLP ----
    const int pwaves = (N + POOL_CHUNK - 1) / POOL_CHUNK;
    pool_kernel<<<(pwaves + 3) / 4, 256, 0, stream>>>(h_b, batch, pooled, N);
    mlp_kernel<<<G, 64, 0, stream>>>(pooled, l1w, l1b, l2w, l2b, out);
}

// Round 12
// 420.605 us; speedup vs baseline: 1.1357x; 1.1357x over previous
//
#include <hip/hip_runtime.h>
#include <hip/hip_bf16.h>

#define BN_EPS 1e-5f

typedef short bf16x8 __attribute__((ext_vector_type(8)));
typedef float f32x4 __attribute__((ext_vector_type(4)));

static __device__ __forceinline__ unsigned short f2bf(float f) {
    unsigned u = __float_as_uint(f);
    unsigned r = (u + 0x7FFF + ((u >> 16) & 1)) >> 16;
    return (unsigned short)r;
}
static __device__ __forceinline__ float bf2f(unsigned short s) {
    return __uint_as_float((unsigned)s << 16);
}
__device__ __forceinline__ int pad8i(int c) { return (c + 7) & ~7; }

#define BIN_SHIFT 9
#define BIN_NODES 512
#define P1_CHUNK 8192
#define IMG_CAP 12288

// ---------------- exclusive scan over PADDED counts (3-pass, chunk = 1024) ----
#define SCAN_CHUNK 1024

__global__ void scan_block_sums(const int* __restrict__ cnt, int* __restrict__ bsums, int n) {
    __shared__ int sdata[256];
    int b = blockIdx.x, t = threadIdx.x;
    int base = b * SCAN_CHUNK;
    int s = 0;
    for (int i = t; i < SCAN_CHUNK; i += 256) {
        int idx = base + i;
        if (idx < n) s += pad8i(cnt[idx]);
    }
    sdata[t] = s;
    __syncthreads();
    for (int off = 128; off > 0; off >>= 1) {
        if (t < off) sdata[t] += sdata[t + off];
        __syncthreads();
    }
    if (t == 0) bsums[b] = sdata[0];
}

__global__ void scan_exclusive_bsums(int* __restrict__ bsums, int nb) {
    if (threadIdx.x == 0 && blockIdx.x == 0) {
        int acc = 0;
        for (int i = 0; i < nb; i++) { int v = bsums[i]; bsums[i] = acc; acc += v; }
    }
}

__global__ void scan_write(const int* __restrict__ cnt, const int* __restrict__ bsums,
                           int* __restrict__ row_start, int n) {
    __shared__ int sdata[256];
    int b = blockIdx.x, t = threadIdx.x;
    int base = b * SCAN_CHUNK + t * 4;
    int v0 = 0, v1 = 0, v2 = 0, v3 = 0;
    if (base + 0 < n) v0 = pad8i(cnt[base + 0]);
    if (base + 1 < n) v1 = pad8i(cnt[base + 1]);
    if (base + 2 < n) v2 = pad8i(cnt[base + 2]);
    if (base + 3 < n) v3 = pad8i(cnt[base + 3]);
    int tsum = v0 + v1 + v2 + v3;
    sdata[t] = tsum;
    __syncthreads();
    for (int off = 1; off < 256; off <<= 1) {       // inclusive Hillis-Steele
        int x = (t >= off) ? sdata[t - off] : 0;
        __syncthreads();
        sdata[t] += x;
        __syncthreads();
    }
    int excl = sdata[t] - tsum + bsums[b];
    if (base + 0 < n) row_start[base + 0] = excl;
    if (base + 1 < n) row_start[base + 1] = excl + v0;
    if (base + 2 < n) row_start[base + 2] = excl + v0 + v1;
    if (base + 3 < n) row_start[base + 3] = excl + v0 + v1 + v2;
    if (n - 1 >= base && n - 1 < base + 4)          // finalize total (padded end)
        row_start[n] = excl + v0 + v1 + v2 + v3;
}

// ---------------- bin-level histogram: LDS hist -> few global atomics -------
__global__ __launch_bounds__(256) void binhist_kernel(const int* __restrict__ dst,
                                                      int* __restrict__ bincnt,
                                                      int e, int nbins) {
    __shared__ int hist[256];
    int t = threadIdx.x;
    hist[t] = 0;
    __syncthreads();
    int c0 = blockIdx.x * P1_CHUNK;
    int iend = c0 + P1_CHUNK; if (iend > e) iend = e;
    for (int i = c0 + t; i < iend; i += 256)
        atomicAdd(&hist[dst[i] >> BIN_SHIFT], 1);
    __syncthreads();
    if (t < nbins && hist[t] > 0) atomicAdd(&bincnt[t], hist[t]);
}

__global__ void scan_small(const int* __restrict__ in, int* __restrict__ out, int m) {
    if (threadIdx.x == 0 && blockIdx.x == 0) {
        int a = 0;
        for (int i = 0; i < m; i++) { out[i] = a; a += in[i]; }
        out[m] = a;
    }
}

// ---------------- phase 1: partition edges into 512-node bins --------------
__global__ __launch_bounds__(256) void phase1_kernel(
        const int* __restrict__ src, const int* __restrict__ dst,
        const int* __restrict__ bstart_e, int* __restrict__ bincur,
        int* __restrict__ ebuf, int e, int nbins) {
    __shared__ int hist[256], base[256], cur[256];
    int t = threadIdx.x;
    int c0 = blockIdx.x * P1_CHUNK;
    int iend = c0 + P1_CHUNK; if (iend > e) iend = e;
    hist[t] = 0;
    __syncthreads();
    for (int i = c0 + t; i < iend; i += 256)
        atomicAdd(&hist[dst[i] >> BIN_SHIFT], 1);
    __syncthreads();
    if (t < nbins && hist[t] > 0)
        base[t] = bstart_e[t] + atomicAdd(&bincur[t], hist[t]);
    cur[t] = 0;
    __syncthreads();
    for (int i = c0 + t; i < iend; i += 256) {
        int s = src[i], d = dst[i];
        int b = d >> BIN_SHIFT;
        int r = atomicAdd(&cur[b], 1);
        ebuf[base[b] + r] = s | ((d & (BIN_NODES - 1)) << 17);
    }
}

// ---------------- per-node counts + dinv from binned edges (LDS only) ------
__global__ __launch_bounds__(256) void bincount_kernel(
        const int* __restrict__ ebuf, const int* __restrict__ bstart_e,
        int* __restrict__ cnt, float* __restrict__ dinv, int n) {
    __shared__ int c512[BIN_NODES];
    int b = blockIdx.x, t = threadIdx.x;
    for (int k = t; k < BIN_NODES; k += 256) c512[k] = 0;
    __syncthreads();
    int e0 = bstart_e[b], e1 = bstart_e[b + 1];
    for (int j = e0 + t; j < e1; j += 256)
        atomicAdd(&c512[ebuf[j] >> 17], 1);
    __syncthreads();
    int n0 = b * BIN_NODES;
    for (int k = t; k < BIN_NODES; k += 256) {
        int i = n0 + k;
        if (i < n) {
            int c = c512[k];
            cnt[i] = c;
            dinv[i] = rsqrtf((float)(c + 1));
        }
    }
}

// ---------------- phase 2: per-bin CSR build in LDS, coalesced write-out ----
__global__ __launch_bounds__(256) void phase2_kernel(
        const int* __restrict__ ebuf, const int* __restrict__ bstart_e,
        const int* __restrict__ row_start, int* __restrict__ csr,
        int* __restrict__ gcursor, int n, int sentinel) {
    __shared__ int image[IMG_CAP];
    __shared__ int lcur[BIN_NODES];
    int b = blockIdx.x, t = threadIdx.x;
    int n0 = b * BIN_NODES;
    int n1 = n0 + BIN_NODES; if (n1 > n) n1 = n;
    int rbase = row_start[n0];
    int rspan = row_start[n1] - rbase;
    int e0 = bstart_e[b], e1 = bstart_e[b + 1];
    for (int k = t; k < BIN_NODES; k += 256) lcur[k] = 0;
    if (rspan <= IMG_CAP) {
        for (int k = t; k < rspan; k += 256) image[k] = sentinel;
        __syncthreads();
        for (int j = e0 + t; j < e1; j += 256) {
            int en = ebuf[j];
            int s = en & 0x1FFFF;
            int dl = en >> 17;
            int pos = row_start[n0 + dl] - rbase + atomicAdd(&lcur[dl], 1);
            image[pos] = s;
        }
        __syncthreads();
        for (int k = t; k < rspan; k += 256) csr[rbase + k] = image[k];
    } else {                                        // statistically never
        __syncthreads();
        for (int j = e0 + t; j < e1; j += 256) {
            int en = ebuf[j];
            int s = en & 0x1FFFF;
            int dl = en >> 17;
            int pos = row_start[n0 + dl] + atomicAdd(&gcursor[n0 + dl], 1);
            csr[pos] = s;
        }
        __syncthreads();
        for (int k = t; k < n1 - n0; k += 256) {    // fill pads with sentinel
            int node = n0 + k;
            int c = gcursor[node];
            for (int pos = row_start[node] + c; pos < row_start[node + 1]; pos++)
                csr[pos] = sentinel;
        }
    }
}

// ---------------- MFMA linear: hs[N,64] = dinv[r] * (in[N,K] @ w[K,64]) ----
// block = 256 thr = 4 waves; 64-row tile; xs + wT staged bf16 in LDS.
// A = wT rows (m = feature), B = xs rows (n = x-row): lane owns 4 consecutive
// features of one row -> ushort4 stores.
template<int K, bool BF16IN>
__global__ __launch_bounds__(256) void lin_mfma(const void* __restrict__ in_,
                                                const float* __restrict__ w,
                                                const float* __restrict__ dinv,
                                                unsigned short* __restrict__ outbf, int n) {
    constexpr int XS = K + 8;                       // shorts; keeps 16B row alignment
    __shared__ unsigned short xs[64 * XS];
    __shared__ unsigned short wt[64 * XS];          // transposed w: wt[col][k]
    int t = threadIdx.x;
    int row0 = blockIdx.x * 64;
    int nrows = n - row0; if (nrows > 64) nrows = 64;

    {   // stage w transposed (float4 reads; scattered 2B LDS writes - small)
        const float4* w4 = (const float4*)w;
        for (int idx = t; idx < K * 16; idx += 256) {
            int k = idx >> 4, c4 = (idx & 15) * 4;
            float4 v = w4[idx];
            wt[(c4 + 0) * XS + k] = f2bf(v.x);
            wt[(c4 + 1) * XS + k] = f2bf(v.y);
            wt[(c4 + 2) * XS + k] = f2bf(v.z);
            wt[(c4 + 3) * XS + k] = f2bf(v.w);
        }
    }
    if constexpr (BF16IN) {
        const uint4* in4 = (const uint4*)((const unsigned short*)in_ + (size_t)row0 * K);
        int total8 = nrows * (K / 8);
        for (int idx = t; idx < total8; idx += 256) {
            int r = idx / (K / 8), kk = idx - r * (K / 8);
            uint4 v = in4[idx];
            *(uint4*)&xs[r * XS + kk * 8] = v;      // 16B aligned
        }
    } else {
        const float4* in4 = (const float4*)((const float*)in_ + (size_t)row0 * K);
        int total4 = nrows * (K / 4);
        for (int idx = t; idx < total4; idx += 256) {
            int r = idx / (K / 4), kk = idx - r * (K / 4);
            float4 v = in4[idx];
            ushort4 s4;
            s4.x = f2bf(v.x); s4.y = f2bf(v.y); s4.z = f2bf(v.z); s4.w = f2bf(v.w);
            *(ushort4*)&xs[r * XS + kk * 4] = s4;   // 8B aligned
        }
    }
    __syncthreads();

    int lane = t & 63;
    int wid = t >> 6;
    int quad = lane >> 4;
    int l15 = lane & 15;

    f32x4 acc[4];
#pragma unroll
    for (int cg = 0; cg < 4; cg++) acc[cg] = (f32x4){0.f, 0.f, 0.f, 0.f};

    const unsigned short* xrow = &xs[(wid * 16 + l15) * XS + quad * 8];
#pragma unroll
    for (int kc = 0; kc < K / 32; kc++) {
        bf16x8 bfrag = *(const bf16x8*)(xrow + kc * 32);
#pragma unroll
        for (int cg = 0; cg < 4; cg++) {
            bf16x8 afrag = *(const bf16x8*)&wt[(cg * 16 + l15) * XS + kc * 32 + quad * 8];
            acc[cg] = __builtin_amdgcn_mfma_f32_16x16x32_bf16(afrag, bfrag, acc[cg], 0, 0, 0);
        }
    }

    int grow = row0 + wid * 16 + l15;               // lane owns one x-row
    if (grow < n) {
        float dv = dinv[grow];
#pragma unroll
        for (int cg = 0; cg < 4; cg++) {            // features cg*16 + quad*4 .. +3
            ushort4 st;
            st.x = f2bf(acc[cg][0] * dv);
            st.y = f2bf(acc[cg][1] * dv);
            st.z = f2bf(acc[cg][2] * dv);
            st.w = f2bf(acc[cg][3] * dv);
            *(ushort4*)&outbf[(size_t)grow * 64 + cg * 16 + quad * 4] = st;
        }
    }
}

// ---------------- aggregation + bias + BN + ReLU (unroll 16, max MLP) ------
// one wave per node, lane = feature; 16 independent row-gathers in flight.
__global__ __launch_bounds__(256) void agg_kernel(
        const unsigned short* __restrict__ hs, const int* __restrict__ row_start,
        const int* __restrict__ csr, const float* __restrict__ dinv,
        const float* __restrict__ bias, const float* __restrict__ gam,
        const float* __restrict__ bet, const float* __restrict__ mu,
        const float* __restrict__ var,
        unsigned short* __restrict__ out, int n) {
    int i = blockIdx.x * 4 + (threadIdx.x >> 6);
    int lane = threadIdx.x & 63;
    if (i >= n) return;
    float acc = bf2f(hs[(size_t)i * 64 + lane]);   // self-loop term (pre-scaled)
    int rs = row_start[i], re = row_start[i + 1];  // multiples of 8
    int j = rs;
    for (; j + 16 <= re; j += 16) {
        int4 c0 = *(const int4*)&csr[j];
        int4 c1 = *(const int4*)&csr[j + 4];
        int4 c2 = *(const int4*)&csr[j + 8];
        int4 c3 = *(const int4*)&csr[j + 12];
        float h0 = bf2f(hs[(size_t)c0.x * 64 + lane]);
        float h1 = bf2f(hs[(size_t)c0.y * 64 + lane]);
        float h2 = bf2f(hs[(size_t)c0.z * 64 + lane]);
        float h3 = bf2f(hs[(size_t)c0.w * 64 + lane]);
        float h4 = bf2f(hs[(size_t)c1.x * 64 + lane]);
        float h5 = bf2f(hs[(size_t)c1.y * 64 + lane]);
        float h6 = bf2f(hs[(size_t)c1.z * 64 + lane]);
        float h7 = bf2f(hs[(size_t)c1.w * 64 + lane]);
        float h8 = bf2f(hs[(size_t)c2.x * 64 + lane]);
        float h9 = bf2f(hs[(size_t)c2.y * 64 + lane]);
        float hA = bf2f(hs[(size_t)c2.z * 64 + lane]);
        float hB = bf2f(hs[(size_t)c2.w * 64 + lane]);
        float hC = bf2f(hs[(size_t)c3.x * 64 + lane]);
        float hD = bf2f(hs[(size_t)c3.y * 64 + lane]);
        float hE = bf2f(hs[(size_t)c3.z * 64 + lane]);
        float hF = bf2f(hs[(size_t)c3.w * 64 + lane]);
        acc += (((h0 + h1) + (h2 + h3)) + ((h4 + h5) + (h6 + h7)))
             + (((h8 + h9) + (hA + hB)) + ((hC + hD) + (hE + hF)));
    }
    for (; j < re; j += 8) {
        int4 c0 = *(const int4*)&csr[j];
        int4 c1 = *(const int4*)&csr[j + 4];
        float h0 = bf2f(hs[(size_t)c0.x * 64 + lane]);
        float h1 = bf2f(hs[(size_t)c0.y * 64 + lane]);
        float h2 = bf2f(hs[(size_t)c0.z * 64 + lane]);
        float h3 = bf2f(hs[(size_t)c0.w * 64 + lane]);
        float h4 = bf2f(hs[(size_t)c1.x * 64 + lane]);
        float h5 = bf2f(hs[(size_t)c1.y * 64 + lane]);
        float h6 = bf2f(hs[(size_t)c1.z * 64 + lane]);
        float h7 = bf2f(hs[(size_t)c1.w * 64 + lane]);
        acc += ((h0 + h1) + (h2 + h3)) + ((h4 + h5) + (h6 + h7));
    }
    float agg = acc * dinv[i];
    float scale = gam[lane] * rsqrtf(var[lane] + BN_EPS);
    float r = (agg + bias[lane] - mu[lane]) * scale + bet[lane];
    out[(size_t)i * 64 + lane] = f2bf(r > 0.f ? r : 0.f);
}

// ---------------- pool stage 1: node-parallel segmented sum (bf16 in) ------
#define POOL_CHUNK 64
__global__ __launch_bounds__(256) void pool_kernel(const unsigned short* __restrict__ h,
                                                   const int* __restrict__ batch,
                                                   float* __restrict__ pooled, int n) {
    int wid = blockIdx.x * 4 + (threadIdx.x >> 6);
    int lane = threadIdx.x & 63;
    int start = wid * POOL_CHUNK;
    if (start >= n) return;
    int end = start + POOL_CHUNK; if (end > n) end = n;
    int cur = batch[start];
    float acc = 0.f;
    for (int i = start; i < end; i++) {
        int b = batch[i];
        if (b != cur) {
            atomicAdd(&pooled[(size_t)cur * 64 + lane], acc);
            acc = 0.f; cur = b;
        }
        acc += bf2f(h[(size_t)i * 64 + lane]);
    }
    atomicAdd(&pooled[(size_t)cur * 64 + lane], acc);
}

// ---------------- pool stage 2: tiny MLP per graph ----------------
__global__ void mlp_kernel(const float* __restrict__ pooled,
                           const float* __restrict__ l1w, const float* __restrict__ l1b,
                           const float* __restrict__ l2w, const float* __restrict__ l2b,
                           float* __restrict__ out) {
    int g = blockIdx.x;
    int lane = threadIdx.x;
    __shared__ float p[64];
    __shared__ float h1[32];
    p[lane] = pooled[(size_t)g * 64 + lane];
    __syncthreads();
    if (lane < 32) {
        float a = l1b[lane];
#pragma unroll 8
        for (int k = 0; k < 64; k++) a += p[k] * l1w[k * 32 + lane];
        h1[lane] = a > 0.f ? a : 0.f;
    }
    __syncthreads();
    if (lane < 2) {
        float a = l2b[lane];
#pragma unroll 8
        for (int j = 0; j < 32; j++) a += h1[j] * l2w[j * 2 + lane];
        out[g * 2 + lane] = a;
    }
}

extern "C" void kernel_launch(void* const* d_in, const int* in_sizes, int n_in,
                              void* d_out, int out_size, void* d_ws, size_t ws_size,
                              hipStream_t stream) {
    const float* x     = (const float*)d_in[0];
    const int*   ei    = (const int*)d_in[1];
    const int*   batch = (const int*)d_in[2];
    const float* w0 = (const float*)d_in[3];
    const float* b0 = (const float*)d_in[4];
    const float* w1 = (const float*)d_in[5];
    const float* b1 = (const float*)d_in[6];
    const float* w2 = (const float*)d_in[7];
    const float* b2 = (const float*)d_in[8];
    const float* g0 = (const float*)d_in[9];
    const float* be0 = (const float*)d_in[10];
    const float* m0 = (const float*)d_in[11];
    const float* v0 = (const float*)d_in[12];
    const float* g1 = (const float*)d_in[13];
    const float* be1 = (const float*)d_in[14];
    const float* m1 = (const float*)d_in[15];
    const float* v1 = (const float*)d_in[16];
    const float* g2 = (const float*)d_in[17];
    const float* be2 = (const float*)d_in[18];
    const float* m2 = (const float*)d_in[19];
    const float* v2 = (const float*)d_in[20];
    const float* l1w = (const float*)d_in[21];
    const float* l1b = (const float*)d_in[22];
    const float* l2w = (const float*)d_in[23];
    const float* l2b = (const float*)d_in[24];
    float* out = (float*)d_out;

    const int N = in_sizes[2];
    const int E = in_sizes[1] / 2;
    const int G = out_size / 2;
    const int NBINS = (N + BIN_NODES - 1) / BIN_NODES;

    const int* src = ei;
    const int* dst = ei + E;

    // workspace layout
    char* p = (char*)d_ws;
    auto alloc = [&](size_t bytes) -> void* {
        void* r = (void*)p;
        p += (bytes + 255) & ~(size_t)255;
        return r;
    };
    const size_t CSR_CAP = ((size_t)E + 8 * (size_t)N + 3) & ~(size_t)3;
    float* dinvp    = (float*)alloc((size_t)N * 4);
    int*   cnt      = (int*)alloc((size_t)N * 4);
    int*   row_start= (int*)alloc((size_t)(N + 1) * 4);
    int*   cursor   = (int*)alloc((size_t)N * 4);
    int    NB       = (N + SCAN_CHUNK - 1) / SCAN_CHUNK;
    int*   bsums    = (int*)alloc((size_t)NB * 4);
    int*   bincnt   = (int*)alloc((size_t)NBINS * 4);
    int*   bstart_e = (int*)alloc((size_t)(NBINS + 1) * 4);
    int*   bincur   = (int*)alloc((size_t)NBINS * 4);
    int*   ebuf     = (int*)alloc((size_t)E * 4);
    int*   csr      = (int*)alloc(CSR_CAP * 4);
    unsigned short* h_a = (unsigned short*)alloc((size_t)(N + 1) * 64 * 2); // +sentinel row
    unsigned short* h_b = (unsigned short*)alloc((size_t)N * 64 * 2);       // bf16 agg out
    float* pooled   = (float*)alloc((size_t)G * 64 * 4);
    (void)ws_size;

    // ---- graph preprocessing ----
    hipMemsetAsync(cursor, 0, (size_t)N * 4, stream);
    hipMemsetAsync(bincnt, 0, (size_t)NBINS * 4, stream);
    hipMemsetAsync(bincur, 0, (size_t)NBINS * 4, stream);
    hipMemsetAsync(pooled, 0, (size_t)G * 64 * 4, stream);
    hipMemsetAsync(h_a + (size_t)N * 64, 0, 64 * 2, stream);   // zero sentinel row
    const int nchunks = (E + P1_CHUNK - 1) / P1_CHUNK;
    binhist_kernel<<<nchunks, 256, 0, stream>>>(dst, bincnt, E, NBINS);
    scan_small<<<1, 64, 0, stream>>>(bincnt, bstart_e, NBINS);
    phase1_kernel<<<nchunks, 256, 0, stream>>>(src, dst, bstart_e, bincur, ebuf, E, NBINS);
    bincount_kernel<<<NBINS, 256, 0, stream>>>(ebuf, bstart_e, cnt, dinvp, N);
    scan_block_sums<<<NB, 256, 0, stream>>>(cnt, bsums, N);
    scan_exclusive_bsums<<<1, 64, 0, stream>>>(bsums, NB);
    scan_write<<<NB, 256, 0, stream>>>(cnt, bsums, row_start, N);
    phase2_kernel<<<NBINS, 256, 0, stream>>>(ebuf, bstart_e, row_start, csr,
                                             cursor, N, N);

    const int nblk = (N + 3) / 4;
    const int lblk = (N + 63) / 64;
    // ---- layer 0 ----
    lin_mfma<128, false><<<lblk, 256, 0, stream>>>(x, w0, dinvp, h_a, N);
    agg_kernel<<<nblk, 256, 0, stream>>>(h_a, row_start, csr, dinvp,
                                         b0, g0, be0, m0, v0, h_b, N);
    // ---- layer 1 ----
    lin_mfma<64, true><<<lblk, 256, 0, stream>>>(h_b, w1, dinvp, h_a, N);
    agg_kernel<<<nblk, 256, 0, stream>>>(h_a, row_start, csr, dinvp,
                                         b1, g1, be1, m1, v1, h_b, N);
    // ---- layer 2 ----
    lin_mfma<64, true><<<lblk, 256, 0, stream>>>(h_b, w2, dinvp, h_a, N);
    agg_kernel<<<nblk, 256, 0, stream>>>(h_a, row_start, csr, dinvp,
                                         b2, g2, be2, m2, v2, h_b, N);
    // ---- pool + MLP ----
    const int pwaves = (N + POOL_CHUNK - 1) / POOL_CHUNK;
    pool_kernel<<<(pwaves + 3) / 4, 256, 0, stream>>>(h_b, batch, pooled, N);
    mlp_kernel<<<G, 64, 0, stream>>>(pooled, l1w, l1b, l2w, l2b, out);
}